// Round 3
// baseline (112.298 us; speedup 1.0000x reference)
//
#include <hip/hip_runtime.h>
#include <stdint.h>

#define NR 8192
#define D 256
#define LOG2E 1.4426950408889634f
#define BM 256          // tile is BM x BM
#define BK 64
#define NKT (D / BK)    // 4 K-tiles
#define TGRID 32        // 8192 / 256
#define NT_SS 528       // 32*33/2 lower-triangle tiles per symmetric block
#define NT_TOT 2080     // 2*528 + 1024

typedef __attribute__((ext_vector_type(8))) short short8;
typedef __attribute__((ext_vector_type(4))) float f32x4;

#if __has_builtin(__builtin_amdgcn_exp2f)
#define EXP2F(x) __builtin_amdgcn_exp2f(x)
#else
#define EXP2F(x) exp2f(x)
#endif

typedef __attribute__((address_space(1))) const void gvoid;
typedef __attribute__((address_space(3))) void lvoid;

__device__ __forceinline__ void gload16(const void* g, void* l) {
    __builtin_amdgcn_global_load_lds((gvoid*)(uintptr_t)g, (lvoid*)(uintptr_t)l,
                                     16, 0, 0);
}

__device__ __forceinline__ unsigned short f2bf(float f) {
    uint32_t u = __float_as_uint(f);
    u += 0x7fffu + ((u >> 16) & 1u);
    return (unsigned short)(u >> 16);
}
__device__ __forceinline__ float bf2f(unsigned short h) {
    return __uint_as_float(((uint32_t)h) << 16);
}

// ---------------- kernel 1: f32 -> bf16 copies + row norms (from bf16 values)
__global__ void prep_kernel(const float* __restrict__ src, const float* __restrict__ tgt,
                            unsigned short* __restrict__ Sb, unsigned short* __restrict__ Tb,
                            float* __restrict__ nS, float* __restrict__ nT) {
    int wid = threadIdx.x >> 6, lane = threadIdx.x & 63;
    int row = blockIdx.x * 4 + wid;
    const float* in; unsigned short* ob; float* on; int r;
    if (row < NR) { in = src; ob = Sb; on = nS; r = row; }
    else         { in = tgt; ob = Tb; on = nT; r = row - NR; }

    const float4* inr = (const float4*)(in + (size_t)r * D);
    float4 v = inr[lane];
    unsigned short b0 = f2bf(v.x), b1 = f2bf(v.y), b2 = f2bf(v.z), b3 = f2bf(v.w);
    float f0 = bf2f(b0), f1 = bf2f(b1), f2 = bf2f(b2), f3 = bf2f(b3);
    float sq = f0 * f0 + f1 * f1 + f2 * f2 + f3 * f3;

    ushort4 pack = make_ushort4(b0, b1, b2, b3);
    *(ushort4*)(ob + (size_t)r * D + lane * 4) = pack;

    #pragma unroll
    for (int o = 32; o > 0; o >>= 1) sq += __shfl_xor(sq, o, 64);
    if (lane == 0) on[r] = -0.5f * LOG2E * sq;
}

// ---------------- kernel 2: 256x256-tile 8-phase MFMA GEMM + exp epilogue
// LDS: As/Bs [2 bufs][256 rows][64 elems] bf16 (128 KB total).
// XOR swizzle (validated r2, conflicts=0): LDS[row][16B-slot s] holds global
// (row, s ^ (row&7)); global_load_lds writes linearly so the inverse
// permutation is applied to the per-lane GLOBAL source address.
__global__ __launch_bounds__(512, 2) void mmd_tiles(
    const unsigned short* __restrict__ Sb, const unsigned short* __restrict__ Tb,
    const float* __restrict__ nS, const float* __restrict__ nT,
    float* __restrict__ parts)
{
    __shared__ unsigned short As[2][BM][BK];   // 64 KB
    __shared__ unsigned short Bs[2][BM][BK];   // 64 KB
    __shared__ float red[8];

    // T1: bijective XCD-chunk swizzle (2080 % 8 == 0 -> chunks of 260)
    int bid = ((int)blockIdx.x & 7) * (NT_TOT / 8) + ((int)blockIdx.x >> 3);

    const unsigned short *Ab, *Bb; const float *nA, *nB; float wgt;
    int ti, tj;
    {
        int idx = bid;
        if (bid < 2 * NT_SS) {
            if (bid >= NT_SS) idx -= NT_SS;
            int t = (int)((sqrtf(8.0f * (float)idx + 1.0f) - 1.0f) * 0.5f);
            while ((t + 1) * (t + 2) / 2 <= idx) ++t;
            while (t * (t + 1) / 2 > idx) --t;
            ti = t; tj = idx - t * (t + 1) / 2;          // tj <= ti
            if (bid < NT_SS) { Ab = Sb; Bb = Sb; nA = nS; nB = nS; }
            else             { Ab = Tb; Bb = Tb; nA = nT; nB = nT; }
            wgt = (ti == tj) ? 1.0f : 2.0f;
        } else {
            idx = bid - 2 * NT_SS;
            ti = idx >> 5; tj = idx & 31;
            Ab = Sb; Bb = Tb; nA = nS; nB = nT;
            wgt = -2.0f;
        }
    }
    const int rowBase = ti * BM, colBase = tj * BM;

    const int tid = threadIdx.x;
    const int wid = tid >> 6, lane = tid & 63;
    const int wr = wid >> 2, wc = wid & 3;       // 2x4 waves; per-wave out 128x64

    // staging: one gload16 covers 8 rows (64 lanes x 16B); 8 gloads/thread/K-tile
    const int srow = lane >> 3;
    const int sslot = (lane & 7) ^ srow;          // inverse swizzle on SOURCE
    const size_t laneOff = (size_t)srow * (D * 2) + (size_t)sslot * 16;
    const char* Agp = (const char*)(Ab + (size_t)rowBase * D);
    const char* Bgp = (const char*)(Bb + (size_t)colBase * D);

    // fragment read offsets: logical 16B slot q=ks*4+hi -> phys q^(fr&7)
    const int fr = lane & 15, hi = lane >> 4;     // hi 0..3
    const int fsw = fr & 7;
    const int eo0 = ((hi) ^ fsw) * 8;             // ks=0 element offset in row
    const int eo1 = ((4 + hi) ^ fsw) * 8;         // ks=1

    f32x4 acc[8][4];
    #pragma unroll
    for (int m = 0; m < 8; ++m)
        #pragma unroll
        for (int n = 0; n < 4; ++n) acc[m][n] = (f32x4){0.f, 0.f, 0.f, 0.f};

    #define STAGE_ALL(b, kt)                                                    \
        do {                                                                    \
            const char* ag = Agp + (size_t)(kt) * (BK * 2) + laneOff;           \
            const char* bg = Bgp + (size_t)(kt) * (BK * 2) + laneOff;           \
            _Pragma("unroll")                                                   \
            for (int i_ = 0; i_ < 2; ++i_) {                                    \
                int r_ = wid * 16 + i_ * 8;                                     \
                gload16(ag + (size_t)r_ * (D * 2),         &As[b][r_][0]);      \
                gload16(ag + (size_t)(r_ + 128) * (D * 2), &As[b][r_ + 128][0]);\
                gload16(bg + (size_t)r_ * (D * 2),         &Bs[b][r_][0]);      \
                gload16(bg + (size_t)(r_ + 128) * (D * 2), &Bs[b][r_ + 128][0]);\
            }                                                                   \
        } while (0)

    #define PHASE_TAIL()                                          \
        __builtin_amdgcn_s_barrier();                             \
        asm volatile("s_waitcnt lgkmcnt(0)" ::: "memory");        \
        __builtin_amdgcn_sched_barrier(0);                        \
        __builtin_amdgcn_s_setprio(1);
    #define PHASE_END()                                           \
        __builtin_amdgcn_s_setprio(0);                            \
        __builtin_amdgcn_s_barrier();

    short8 af[4][2];     // one m-half (4 frags x 2 kslots)
    short8 bf0[2][2];    // n-half 0 (n=0,1)
    short8 bf1[2][2];    // n-half 1 (n=2,3)

    // prologue: stage K-tile 0 into buf0
    STAGE_ALL(0, 0);
    asm volatile("s_waitcnt vmcnt(0)" ::: "memory");
    __builtin_amdgcn_s_barrier();

    for (int kt = 0; kt < NKT; ++kt) {
        const int cur = kt & 1;
        const unsigned short* Ap = &As[cur][0][0];
        const unsigned short* Bp = &Bs[cur][0][0];

        // ---- P0: read af(mh0) + bf(nh0); issue all next-K-tile stages
        #pragma unroll
        for (int m = 0; m < 4; ++m) {
            int r = (wr * 128 + m * 16 + fr) * BK;
            af[m][0] = *(const short8*)(Ap + r + eo0);
            af[m][1] = *(const short8*)(Ap + r + eo1);
        }
        #pragma unroll
        for (int n = 0; n < 2; ++n) {
            int r = (wc * 64 + n * 16 + fr) * BK;
            bf0[n][0] = *(const short8*)(Bp + r + eo0);
            bf0[n][1] = *(const short8*)(Bp + r + eo1);
        }
        if (kt + 1 < NKT) STAGE_ALL(cur ^ 1, kt + 1);
        PHASE_TAIL();
        #pragma unroll
        for (int m = 0; m < 4; ++m)
            #pragma unroll
            for (int n = 0; n < 2; ++n)
                #pragma unroll
                for (int ks = 0; ks < 2; ++ks)
                    acc[m][n] = __builtin_amdgcn_mfma_f32_16x16x32_bf16(
                        af[m][ks], bf0[n][ks], acc[m][n], 0, 0, 0);
        PHASE_END();

        // ---- P1: read bf(nh1); MFMA mh0 x nh1
        #pragma unroll
        for (int n = 0; n < 2; ++n) {
            int r = (wc * 64 + (n + 2) * 16 + fr) * BK;
            bf1[n][0] = *(const short8*)(Bp + r + eo0);
            bf1[n][1] = *(const short8*)(Bp + r + eo1);
        }
        PHASE_TAIL();
        #pragma unroll
        for (int m = 0; m < 4; ++m)
            #pragma unroll
            for (int n = 0; n < 2; ++n)
                #pragma unroll
                for (int ks = 0; ks < 2; ++ks)
                    acc[m][n + 2] = __builtin_amdgcn_mfma_f32_16x16x32_bf16(
                        af[m][ks], bf1[n][ks], acc[m][n + 2], 0, 0, 0);
        PHASE_END();

        // ---- P2: read af(mh1); MFMA mh1 x nh1 (bf1 still live)
        #pragma unroll
        for (int m = 0; m < 4; ++m) {
            int r = (wr * 128 + (m + 4) * 16 + fr) * BK;
            af[m][0] = *(const short8*)(Ap + r + eo0);
            af[m][1] = *(const short8*)(Ap + r + eo1);
        }
        PHASE_TAIL();
        #pragma unroll
        for (int m = 0; m < 4; ++m)
            #pragma unroll
            for (int n = 0; n < 2; ++n)
                #pragma unroll
                for (int ks = 0; ks < 2; ++ks)
                    acc[m + 4][n + 2] = __builtin_amdgcn_mfma_f32_16x16x32_bf16(
                        af[m][ks], bf1[n][ks], acc[m + 4][n + 2], 0, 0, 0);
        PHASE_END();

        // ---- P3: no reads; MFMA mh1 x nh0 (bf0 still live); K-tile boundary
        PHASE_TAIL();
        #pragma unroll
        for (int m = 0; m < 4; ++m)
            #pragma unroll
            for (int n = 0; n < 2; ++n)
                #pragma unroll
                for (int ks = 0; ks < 2; ++ks)
                    acc[m + 4][n] = __builtin_amdgcn_mfma_f32_16x16x32_bf16(
                        af[m][ks], bf0[n][ks], acc[m + 4][n], 0, 0, 0);
        __builtin_amdgcn_s_setprio(0);
        if (kt + 1 < NKT) asm volatile("s_waitcnt vmcnt(0)" ::: "memory");
        __builtin_amdgcn_s_barrier();
    }
    #undef STAGE_ALL
    #undef PHASE_TAIL
    #undef PHASE_END

    // epilogue: u = exp2(log2e*xy + bx_i + cy_j); contrib = u + u^2
    float lsum = 0.0f;
    {
        float cy[4]; f32x4 bx[8];
        #pragma unroll
        for (int n = 0; n < 4; ++n) cy[n] = nB[colBase + wc * 64 + n * 16 + fr];
        #pragma unroll
        for (int m = 0; m < 8; ++m)
            bx[m] = *(const f32x4*)&nA[rowBase + wr * 128 + m * 16 + hi * 4];
        #pragma unroll
        for (int m = 0; m < 8; ++m)
            #pragma unroll
            for (int n = 0; n < 4; ++n) {
                float bc0 = cy[n];
                #pragma unroll
                for (int r = 0; r < 4; ++r) {
                    float arg = fmaf(acc[m][n][r], LOG2E, bx[m][r] + bc0);
                    float u = EXP2F(arg);
                    lsum = fmaf(u, u, lsum) + u;
                }
            }
    }
    #pragma unroll
    for (int o = 32; o > 0; o >>= 1) lsum += __shfl_xor(lsum, o, 64);
    if (lane == 0) red[wid] = lsum;
    __syncthreads();
    if (tid == 0) {
        float s = 0.0f;
        #pragma unroll
        for (int w = 0; w < 8; ++w) s += red[w];
        parts[bid] = wgt * s;
    }
}

// ---------------- kernel 3: final deterministic reduction
__global__ void reduce_parts(const float* __restrict__ parts, float* __restrict__ out) {
    __shared__ float buf[256];
    float s = 0.0f;
    for (int i = threadIdx.x; i < NT_TOT; i += 256) s += parts[i];
    buf[threadIdx.x] = s;
    __syncthreads();
    #pragma unroll
    for (int st = 128; st > 0; st >>= 1) {
        if ((int)threadIdx.x < st) buf[threadIdx.x] += buf[threadIdx.x + st];
        __syncthreads();
    }
    if (threadIdx.x == 0) out[0] = buf[0] * (1.0f / 67108864.0f);  // /8192^2
}

extern "C" void kernel_launch(void* const* d_in, const int* in_sizes, int n_in,
                              void* d_out, int out_size, void* d_ws, size_t ws_size,
                              hipStream_t stream) {
    const float* src = (const float*)d_in[0];
    const float* tgt = (const float*)d_in[1];

    char* w = (char*)d_ws;
    unsigned short* Sb = (unsigned short*)w;
    unsigned short* Tb = (unsigned short*)(w + (size_t)NR * D * 2);
    float* nS = (float*)(w + 2 * (size_t)NR * D * 2);
    float* nT = nS + NR;
    float* parts = nT + NR;

    hipLaunchKernelGGL(prep_kernel, dim3(NR * 2 / 4), dim3(256), 0, stream,
                       src, tgt, Sb, Tb, nS, nT);
    hipLaunchKernelGGL(mmd_tiles, dim3(NT_TOT), dim3(512), 0, stream,
                       Sb, Tb, nS, nT, parts);
    hipLaunchKernelGGL(reduce_parts, dim3(1), dim3(256), 0, stream,
                       parts, (float*)d_out);
}

// Round 4
// 85.200 us; speedup vs baseline: 1.3181x; 1.3181x over previous
//
#include <hip/hip_runtime.h>
#include <hip/hip_fp8.h>
#include <stdint.h>

#define NR 8192
#define D 256            // elements per row == bytes per row in fp8
#define LOG2E 1.4426950408889634f
#define BM 256           // tile is BM x BM
#define TGRID 32         // 8192 / 256
#define NT_SS 528        // 32*33/2 lower-triangle tiles per symmetric block
#define NT_TOT 2080      // 2*528 + 1024

typedef __attribute__((ext_vector_type(4))) float f32x4;

#if __has_builtin(__builtin_amdgcn_exp2f)
#define EXP2F(x) __builtin_amdgcn_exp2f(x)
#else
#define EXP2F(x) exp2f(x)
#endif

typedef __attribute__((address_space(1))) const void gvoid;
typedef __attribute__((address_space(3))) void lvoid;

__device__ __forceinline__ void gload16(const void* g, void* l) {
    // async global->LDS, 16B/lane; LDS dest is wave-uniform base + lane*16
    __builtin_amdgcn_global_load_lds((gvoid*)(uintptr_t)g, (lvoid*)(uintptr_t)l,
                                     16, 0, 0);
}

// ---------------- kernel 1: f32 -> fp8 e4m3 copies + row norms (from the
// QUANTIZED values, so diagonal l2 = n_i + n_i - 2*q.q ~= 0 exactly)
__global__ void prep_kernel(const float* __restrict__ src, const float* __restrict__ tgt,
                            unsigned char* __restrict__ Sq, unsigned char* __restrict__ Tq,
                            float* __restrict__ nS, float* __restrict__ nT) {
    int wid = threadIdx.x >> 6, lane = threadIdx.x & 63;
    int row = blockIdx.x * 4 + wid;            // 0..16383
    const float* in; unsigned char* ob; float* on; int r;
    if (row < NR) { in = src; ob = Sq; on = nS; r = row; }
    else         { in = tgt; ob = Tq; on = nT; r = row - NR; }

    const float4* inr = (const float4*)(in + (size_t)r * D);
    float4 v = inr[lane];                       // 256 cols / 64 lanes = 4 f32
    __hip_fp8_e4m3 q0(v.x), q1(v.y), q2(v.z), q3(v.w);
    float f0 = (float)q0, f1 = (float)q1, f2 = (float)q2, f3 = (float)q3;
    float sq = f0 * f0 + f1 * f1 + f2 * f2 + f3 * f3;

    uint32_t pack = (uint32_t)q0.__x | ((uint32_t)q1.__x << 8) |
                    ((uint32_t)q2.__x << 16) | ((uint32_t)q3.__x << 24);
    *(uint32_t*)(ob + (size_t)r * D + lane * 4) = pack;

    #pragma unroll
    for (int o = 32; o > 0; o >>= 1) sq += __shfl_xor(sq, o, 64);
    if (lane == 0) on[r] = -0.5f * LOG2E * sq;  // b_i = -(log2e/2)*||x_i||^2
}

// ---------------- kernel 2: 256x256-tile fp8 MFMA GEMM + exp epilogue
// LDS: single-buffer As/Bs [256 rows][128 B] fp8 (64 KB) -> 2 blocks/CU.
// K=256 split into 2 halves of 128 B; stage->sync->compute per half; the
// co-resident block covers staging latency (r2-proven mechanism).
// XOR swizzle (r2-validated, conflicts=0): LDS[row][16B-slot p] holds global
// slot p ^ (row&7); inverse applied on the per-lane GLOBAL source address.
__global__ __launch_bounds__(512, 2) void mmd_tiles(
    const unsigned char* __restrict__ Sq, const unsigned char* __restrict__ Tq,
    const float* __restrict__ nS, const float* __restrict__ nT,
    float* __restrict__ parts)
{
    __shared__ __align__(16) unsigned char As[BM][128];   // 32 KB
    __shared__ __align__(16) unsigned char Bs[BM][128];   // 32 KB
    __shared__ float red[8];

    // T1: bijective XCD-chunk swizzle (2080 % 8 == 0 -> chunks of 260);
    // contiguous chunks keep an XCD's panel set (~<=2MB fp8) inside its L2.
    int bid = ((int)blockIdx.x & 7) * (NT_TOT / 8) + ((int)blockIdx.x >> 3);

    const unsigned char *Ab, *Bb; const float *nA, *nB; float wgt;
    int ti, tj;
    {
        int idx = bid;
        if (bid < 2 * NT_SS) {
            if (bid >= NT_SS) idx -= NT_SS;
            int t = (int)((sqrtf(8.0f * (float)idx + 1.0f) - 1.0f) * 0.5f);
            while ((t + 1) * (t + 2) / 2 <= idx) ++t;
            while (t * (t + 1) / 2 > idx) --t;
            ti = t; tj = idx - t * (t + 1) / 2;          // tj <= ti
            if (bid < NT_SS) { Ab = Sq; Bb = Sq; nA = nS; nB = nS; }
            else             { Ab = Tq; Bb = Tq; nA = nT; nB = nT; }
            wgt = (ti == tj) ? 1.0f : 2.0f;              // symmetric double-count
        } else {
            idx = bid - 2 * NT_SS;
            ti = idx >> 5; tj = idx & 31;
            Ab = Sq; Bb = Tq; nA = nS; nB = nT;
            wgt = -2.0f;                                  // -2 * mean(s,t)
        }
    }
    const int rowBase = ti * BM, colBase = tj * BM;

    const int tid = threadIdx.x;
    const int wid = tid >> 6, lane = tid & 63;
    const int wr = wid >> 2, wc = wid & 3;       // 2x4 waves; per-wave out 128x64

    // staging: one gload16 covers 8 rows (64 lanes x 16B = 1KB)
    const int srow = lane >> 3;                   // 0..7
    const int sslot = (lane & 7) ^ srow;          // inverse swizzle on SOURCE
    const size_t laneOff = (size_t)srow * D + (size_t)sslot * 16;
    const unsigned char* Agp = Ab + (size_t)rowBase * D;
    const unsigned char* Bgp = Bb + (size_t)colBase * D;

    const int fr = lane & 15, hi = lane >> 4;     // hi 0..3
    const int bo = (hi & 1) * 8;                  // byte within 16B slot

    f32x4 acc[8][4];
    #pragma unroll
    for (int m = 0; m < 8; ++m)
        #pragma unroll
        for (int n = 0; n < 4; ++n) acc[m][n] = (f32x4){0.f, 0.f, 0.f, 0.f};

    // 32 chunks of 8 rows per matrix; 8 waves x 4 chunks each
    #define STAGE(kt)                                                           \
        do {                                                                    \
            const unsigned char* ag = Agp + (size_t)(kt) * 128 + laneOff;       \
            const unsigned char* bg = Bgp + (size_t)(kt) * 128 + laneOff;       \
            _Pragma("unroll")                                                   \
            for (int c_ = 0; c_ < 4; ++c_) {                                    \
                int ch = wid * 4 + c_;                                          \
                gload16(ag + (size_t)(ch * 8) * D, &As[ch * 8][0]);             \
                gload16(bg + (size_t)(ch * 8) * D, &Bs[ch * 8][0]);             \
            }                                                                   \
        } while (0)

    // per K-half: 4 k-steps of 32; A frag = 8B/lane at logical byte 32*ks+8*hi
    #define COMPUTE()                                                           \
        _Pragma("unroll")                                                       \
        for (int ks = 0; ks < 4; ++ks) {                                        \
            const int ls = 2 * ks + (hi >> 1);    /* logical 16B slot */        \
            long af[8]; long bfv[4];                                            \
            _Pragma("unroll")                                                   \
            for (int m = 0; m < 8; ++m) {                                       \
                int rw = wr * 128 + m * 16 + fr;                                \
                af[m] = *(const long*)(&As[rw][((ls ^ (rw & 7)) * 16) + bo]);   \
            }                                                                   \
            _Pragma("unroll")                                                   \
            for (int n = 0; n < 4; ++n) {                                       \
                int rw = wc * 64 + n * 16 + fr;                                 \
                bfv[n] = *(const long*)(&Bs[rw][((ls ^ (rw & 7)) * 16) + bo]);  \
            }                                                                   \
            _Pragma("unroll")                                                   \
            for (int m = 0; m < 8; ++m)                                         \
                _Pragma("unroll")                                               \
                for (int n = 0; n < 4; ++n)                                     \
                    acc[m][n] = __builtin_amdgcn_mfma_f32_16x16x32_fp8_fp8(     \
                        af[m], bfv[n], acc[m][n], 0, 0, 0);                     \
        }

    STAGE(0);
    __syncthreads();          // drains vmcnt, then barrier
    COMPUTE();
    __syncthreads();          // all waves done reading LDS before overwrite
    STAGE(1);
    __syncthreads();
    COMPUTE();
    #undef STAGE
    #undef COMPUTE

    // epilogue: u = exp2(log2e*xy + bx_i + cy_j); contrib = u + u^2
    float lsum = 0.0f;
    {
        float cy[4]; f32x4 bx[8];
        #pragma unroll
        for (int n = 0; n < 4; ++n) cy[n] = nB[colBase + wc * 64 + n * 16 + fr];
        #pragma unroll
        for (int m = 0; m < 8; ++m)
            bx[m] = *(const f32x4*)&nA[rowBase + wr * 128 + m * 16 + hi * 4];
        #pragma unroll
        for (int m = 0; m < 8; ++m)
            #pragma unroll
            for (int n = 0; n < 4; ++n) {
                float bc0 = cy[n];
                #pragma unroll
                for (int r = 0; r < 4; ++r) {
                    float arg = fmaf(acc[m][n][r], LOG2E, bx[m][r] + bc0);
                    float u = EXP2F(arg);   // underflows to 0 for far pairs
                    lsum = fmaf(u, u, lsum) + u;
                }
            }
    }
    #pragma unroll
    for (int o = 32; o > 0; o >>= 1) lsum += __shfl_xor(lsum, o, 64);
    if (lane == 0) red[wid] = lsum;
    __syncthreads();
    if (tid == 0) {
        float s = 0.0f;
        #pragma unroll
        for (int w = 0; w < 8; ++w) s += red[w];
        parts[bid] = wgt * s;
    }
}

// ---------------- kernel 3: final deterministic reduction
__global__ void reduce_parts(const float* __restrict__ parts, float* __restrict__ out) {
    __shared__ float buf[256];
    float s = 0.0f;
    for (int i = threadIdx.x; i < NT_TOT; i += 256) s += parts[i];
    buf[threadIdx.x] = s;
    __syncthreads();
    #pragma unroll
    for (int st = 128; st > 0; st >>= 1) {
        if ((int)threadIdx.x < st) buf[threadIdx.x] += buf[threadIdx.x + st];
        __syncthreads();
    }
    if (threadIdx.x == 0) out[0] = buf[0] * (1.0f / 67108864.0f);  // /8192^2
}

extern "C" void kernel_launch(void* const* d_in, const int* in_sizes, int n_in,
                              void* d_out, int out_size, void* d_ws, size_t ws_size,
                              hipStream_t stream) {
    const float* src = (const float*)d_in[0];
    const float* tgt = (const float*)d_in[1];

    // ws layout: Sq (2MB) | Tq (2MB) | nS (32KB) | nT (32KB) | parts (8.3KB)
    char* w = (char*)d_ws;
    unsigned char* Sq = (unsigned char*)w;
    unsigned char* Tq = (unsigned char*)(w + (size_t)NR * D);
    float* nS = (float*)(w + 2 * (size_t)NR * D);
    float* nT = nS + NR;
    float* parts = nT + NR;

    hipLaunchKernelGGL(prep_kernel, dim3(NR * 2 / 4), dim3(256), 0, stream,
                       src, tgt, Sq, Tq, nS, nT);
    hipLaunchKernelGGL(mmd_tiles, dim3(NT_TOT), dim3(512), 0, stream,
                       Sq, Tq, nS, nT, parts);
    hipLaunchKernelGGL(reduce_parts, dim3(1), dim3(256), 0, stream,
                       parts, (float*)d_out);
}

// Round 5
// 55.427 us; speedup vs baseline: 2.0261x; 1.5372x over previous
//
#include <hip/hip_runtime.h>
#include <hip/hip_fp8.h>
#include <stdint.h>

#define NR 8192
#define D 256            // elements per row == bytes per row in fp8
#define LOG2E 1.4426950408889634f
#define BM 256           // tile is BM x BM
#define NT_SS 528        // 32*33/2 lower-triangle tiles per symmetric block
#define NT_TOT 2080      // 2*528 + 1024

typedef __attribute__((ext_vector_type(4))) float f32x4;
typedef __attribute__((ext_vector_type(16))) float f32x16;
typedef __attribute__((ext_vector_type(4))) int int4v;
typedef __attribute__((ext_vector_type(8))) int int8v;

#if __has_builtin(__builtin_amdgcn_exp2f)
#define EXP2F(x) __builtin_amdgcn_exp2f(x)
#else
#define EXP2F(x) exp2f(x)
#endif

typedef __attribute__((address_space(1))) const void gvoid;
typedef __attribute__((address_space(3))) void lvoid;

__device__ __forceinline__ void gload16(const void* g, void* l) {
    // async global->LDS, 16B/lane; LDS dest is wave-uniform base + lane*16
    __builtin_amdgcn_global_load_lds((gvoid*)(uintptr_t)g, (lvoid*)(uintptr_t)l,
                                     16, 0, 0);
}

// ---------------- kernel 1: f32 -> fp8 e4m3 copies + row norms (from the
// QUANTIZED values, so diagonal l2 = n_i + n_i - 2*q.q ~= 0 exactly)
__global__ void prep_kernel(const float* __restrict__ src, const float* __restrict__ tgt,
                            unsigned char* __restrict__ Sq, unsigned char* __restrict__ Tq,
                            float* __restrict__ nS, float* __restrict__ nT) {
    int wid = threadIdx.x >> 6, lane = threadIdx.x & 63;
    int row = blockIdx.x * 4 + wid;            // 0..16383
    const float* in; unsigned char* ob; float* on; int r;
    if (row < NR) { in = src; ob = Sq; on = nS; r = row; }
    else         { in = tgt; ob = Tq; on = nT; r = row - NR; }

    const float4* inr = (const float4*)(in + (size_t)r * D);
    float4 v = inr[lane];                       // 256 cols / 64 lanes = 4 f32
    __hip_fp8_e4m3 q0(v.x), q1(v.y), q2(v.z), q3(v.w);
    float f0 = (float)q0, f1 = (float)q1, f2 = (float)q2, f3 = (float)q3;
    float sq = f0 * f0 + f1 * f1 + f2 * f2 + f3 * f3;

    uint32_t pack = (uint32_t)q0.__x | ((uint32_t)q1.__x << 8) |
                    ((uint32_t)q2.__x << 16) | ((uint32_t)q3.__x << 24);
    *(uint32_t*)(ob + (size_t)r * D + lane * 4) = pack;

    #pragma unroll
    for (int o = 32; o > 0; o >>= 1) sq += __shfl_xor(sq, o, 64);
    if (lane == 0) on[r] = -0.5f * LOG2E * sq;  // b_i = -(log2e/2)*||x_i||^2
}

// ---------------- kernel 2: 256x256-tile MX-fp8 MFMA GEMM + exp epilogue
// MFMA: mfma_scale_f32_32x32x64_f8f6f4, FMT=0 (fp8 e4m3), scale=2^0 (=127).
// A/B operand layout: lane: row/col = l&31, k-bytes = 32*(l>>5) .. +31.
// LDS: As/Bs [2 bufs][256 rows][128 B], double-buffered K-halves (128 KB).
// XOR swizzle (r2/r4-validated): LDS[row][16B-slot p] holds global slot
// p ^ (row&7); inverse applied on the per-lane GLOBAL source address.
__global__ __launch_bounds__(512, 2) void mmd_tiles(
    const unsigned char* __restrict__ Sq, const unsigned char* __restrict__ Tq,
    const float* __restrict__ nS, const float* __restrict__ nT,
    float* __restrict__ parts)
{
    __shared__ __align__(16) unsigned char As[2][BM][128];   // 64 KB
    __shared__ __align__(16) unsigned char Bs[2][BM][128];   // 64 KB
    __shared__ float red[8];

    // T1: bijective XCD-chunk swizzle (2080 % 8 == 0 -> chunks of 260)
    int bid = ((int)blockIdx.x & 7) * (NT_TOT / 8) + ((int)blockIdx.x >> 3);

    const unsigned char *Ab, *Bb; const float *nA, *nB; float wgt;
    int ti, tj;
    {
        int idx = bid;
        if (bid < 2 * NT_SS) {
            if (bid >= NT_SS) idx -= NT_SS;
            int t = (int)((sqrtf(8.0f * (float)idx + 1.0f) - 1.0f) * 0.5f);
            while ((t + 1) * (t + 2) / 2 <= idx) ++t;
            while (t * (t + 1) / 2 > idx) --t;
            ti = t; tj = idx - t * (t + 1) / 2;          // tj <= ti
            if (bid < NT_SS) { Ab = Sq; Bb = Sq; nA = nS; nB = nS; }
            else             { Ab = Tq; Bb = Tq; nA = nT; nB = nT; }
            wgt = (ti == tj) ? 1.0f : 2.0f;              // symmetric double-count
        } else {
            idx = bid - 2 * NT_SS;
            ti = idx >> 5; tj = idx & 31;
            Ab = Sq; Bb = Tq; nA = nS; nB = nT;
            wgt = -2.0f;                                  // -2 * mean(s,t)
        }
    }
    const int rowBase = ti * BM, colBase = tj * BM;

    const int tid = threadIdx.x;
    const int wid = tid >> 6, lane = tid & 63;
    const int wr = wid >> 2, wc = wid & 3;       // 2x4 waves; per-wave out 128x64
    const int l31 = lane & 31, h2 = lane >> 5;   // MFMA row/col, k-half

    // staging: one gload16 covers 8 rows (64 lanes x 16B = 1KB)
    const int srow = lane >> 3;                   // 0..7
    const int sslot = (lane & 7) ^ srow;          // inverse swizzle on SOURCE
    const size_t laneOff = (size_t)srow * D + (size_t)sslot * 16;
    const unsigned char* Agp = Ab + (size_t)rowBase * D;
    const unsigned char* Bgp = Bb + (size_t)colBase * D;

    f32x16 acc[4][2];
    {
        f32x16 z = {};
        #pragma unroll
        for (int m = 0; m < 4; ++m) { acc[m][0] = z; acc[m][1] = z; }
    }

    // stage one K-half (128 B per row) of both matrices into buffer b
    #define STAGE(b, kt)                                                        \
        do {                                                                    \
            const unsigned char* ag = Agp + (size_t)(kt) * 128 + laneOff;       \
            const unsigned char* bg = Bgp + (size_t)(kt) * 128 + laneOff;       \
            _Pragma("unroll")                                                   \
            for (int c_ = 0; c_ < 4; ++c_) {                                    \
                int ch = wid * 4 + c_;            /* 8-row chunk 0..31 */       \
                gload16(ag + (size_t)(ch * 8) * D, &As[b][ch * 8][0]);          \
                gload16(bg + (size_t)(ch * 8) * D, &Bs[b][ch * 8][0]);          \
            }                                                                   \
        } while (0)

    // one K-half = 2 k-slices of 64; per slice each lane reads 32 contiguous
    // logical k-bytes = 2 x b128 at phys slots p0, p0^1
    #define COMPUTE(b)                                                          \
        _Pragma("unroll")                                                       \
        for (int q = 0; q < 2; ++q) {                                           \
            int8v bfv[2];                                                       \
            _Pragma("unroll")                                                   \
            for (int ni = 0; ni < 2; ++ni) {                                    \
                int rb = wc * 64 + ni * 32 + l31;                               \
                const unsigned char* rp = &Bs[b][rb][0];                        \
                int p0 = ((4 * q + 2 * h2) ^ (rb & 7)) * 16;                    \
                int4v lo = *(const int4v*)(rp + p0);                            \
                int4v hi = *(const int4v*)(rp + (p0 ^ 16));                     \
                bfv[ni] = __builtin_shufflevector(lo, hi, 0,1,2,3,4,5,6,7);     \
            }                                                                   \
            _Pragma("unroll")                                                   \
            for (int mi = 0; mi < 4; ++mi) {                                    \
                int ra = wr * 128 + mi * 32 + l31;                              \
                const unsigned char* rp = &As[b][ra][0];                        \
                int p0 = ((4 * q + 2 * h2) ^ (ra & 7)) * 16;                    \
                int4v lo = *(const int4v*)(rp + p0);                            \
                int4v hi = *(const int4v*)(rp + (p0 ^ 16));                     \
                int8v a = __builtin_shufflevector(lo, hi, 0,1,2,3,4,5,6,7);     \
                acc[mi][0] = __builtin_amdgcn_mfma_scale_f32_32x32x64_f8f6f4(   \
                    a, bfv[0], acc[mi][0], 0, 0, 0, 127, 0, 127);               \
                acc[mi][1] = __builtin_amdgcn_mfma_scale_f32_32x32x64_f8f6f4(   \
                    a, bfv[1], acc[mi][1], 0, 0, 0, 127, 0, 127);               \
            }                                                                   \
        }

    STAGE(0, 0);
    __syncthreads();          // drains vmcnt(0), then barrier
    STAGE(1, 1);              // in flight while computing half 0
    COMPUTE(0);
    __syncthreads();          // drains vmcnt(0) for half 1 + LDS reuse barrier
    COMPUTE(1);
    #undef STAGE
    #undef COMPUTE

    // epilogue: arg = log2e*xy + bx_i + cy_j; contrib = u + u^2, u = exp2(arg)
    // C/D layout (32x32): col = lane&31, row = (reg&3) + 8*(reg>>2) + 4*(lane>>5)
    float lsum = 0.0f;
    {
        f32x4 bx[4][4]; float cy[2];
        #pragma unroll
        for (int mi = 0; mi < 4; ++mi)
            #pragma unroll
            for (int g = 0; g < 4; ++g)
                bx[mi][g] = *(const f32x4*)&nA[rowBase + wr * 128 + mi * 32 + 4 * h2 + 8 * g];
        #pragma unroll
        for (int ni = 0; ni < 2; ++ni)
            cy[ni] = nB[colBase + wc * 64 + ni * 32 + l31];

        // conservative skip bound: max over this wave's region of
        // log2e*acc + bx + cy; if < -160 every exp2 underflows to exact 0
        float macc = -3.0e38f, mbx = -3.0e38f;
        #pragma unroll
        for (int mi = 0; mi < 4; ++mi) {
            #pragma unroll
            for (int ni = 0; ni < 2; ++ni)
                #pragma unroll
                for (int r = 0; r < 16; ++r) macc = fmaxf(macc, acc[mi][ni][r]);
            #pragma unroll
            for (int g = 0; g < 4; ++g)
                #pragma unroll
                for (int j = 0; j < 4; ++j) mbx = fmaxf(mbx, bx[mi][g][j]);
        }
        float bound = fmaf(macc, LOG2E, mbx + fmaxf(cy[0], cy[1]));
        #pragma unroll
        for (int o = 32; o > 0; o >>= 1)
            bound = fmaxf(bound, __shfl_xor(bound, o, 64));

        if (bound >= -160.0f) {
            float s0 = 0.f, s1 = 0.f, s2 = 0.f, s3 = 0.f;
            #pragma unroll
            for (int mi = 0; mi < 4; ++mi)
                #pragma unroll
                for (int ni = 0; ni < 2; ++ni) {
                    float c0 = cy[ni];
                    #pragma unroll
                    for (int r = 0; r < 16; ++r) {
                        float arg = fmaf(acc[mi][ni][r], LOG2E, bx[mi][r >> 2][r & 3] + c0);
                        float u = EXP2F(arg);
                        float t = fmaf(u, u, u);         // u^2 + u
                        if ((r & 3) == 0) s0 += t;
                        else if ((r & 3) == 1) s1 += t;
                        else if ((r & 3) == 2) s2 += t;
                        else s3 += t;
                    }
                }
            lsum = (s0 + s1) + (s2 + s3);
        }
    }
    #pragma unroll
    for (int o = 32; o > 0; o >>= 1) lsum += __shfl_xor(lsum, o, 64);
    if (lane == 0) red[wid] = lsum;
    __syncthreads();
    if (tid == 0) {
        float s = 0.0f;
        #pragma unroll
        for (int w = 0; w < 8; ++w) s += red[w];
        parts[bid] = wgt * s;
    }
}

// ---------------- kernel 3: final deterministic reduction
__global__ void reduce_parts(const float* __restrict__ parts, float* __restrict__ out) {
    __shared__ float buf[256];
    float s = 0.0f;
    for (int i = threadIdx.x; i < NT_TOT; i += 256) s += parts[i];
    buf[threadIdx.x] = s;
    __syncthreads();
    #pragma unroll
    for (int st = 128; st > 0; st >>= 1) {
        if ((int)threadIdx.x < st) buf[threadIdx.x] += buf[threadIdx.x + st];
        __syncthreads();
    }
    if (threadIdx.x == 0) out[0] = buf[0] * (1.0f / 67108864.0f);  // /8192^2
}

extern "C" void kernel_launch(void* const* d_in, const int* in_sizes, int n_in,
                              void* d_out, int out_size, void* d_ws, size_t ws_size,
                              hipStream_t stream) {
    const float* src = (const float*)d_in[0];
    const float* tgt = (const float*)d_in[1];

    // ws layout: Sq (2MB) | Tq (2MB) | nS (32KB) | nT (32KB) | parts (8.3KB)
    char* w = (char*)d_ws;
    unsigned char* Sq = (unsigned char*)w;
    unsigned char* Tq = (unsigned char*)(w + (size_t)NR * D);
    float* nS = (float*)(w + 2 * (size_t)NR * D);
    float* nT = nS + NR;
    float* parts = nT + NR;

    hipLaunchKernelGGL(prep_kernel, dim3(NR * 2 / 4), dim3(256), 0, stream,
                       src, tgt, Sq, Tq, nS, nT);
    hipLaunchKernelGGL(mmd_tiles, dim3(NT_TOT), dim3(512), 0, stream,
                       Sq, Tq, nS, nT, parts);
    hipLaunchKernelGGL(reduce_parts, dim3(1), dim3(256), 0, stream,
                       parts, (float*)d_out);
}

// Round 6
// 36.694 us; speedup vs baseline: 3.0604x; 1.5105x over previous
//
#include <hip/hip_runtime.h>
#include <stdint.h>

#define NR 8192
#define RB 128           // bytes per row in fp4 (256 elems * 0.5 B)
#define LOG2E 1.4426950408889634f
#define BM 256           // tile is BM x BM
#define NT_SS 528        // 32*33/2 lower-triangle tiles per symmetric block
#define NT_TOT 2080      // 2*528 + 1024
#define NBLK 256         // persistent blocks (1 per CU)

typedef __attribute__((ext_vector_type(4))) float f32x4;
typedef __attribute__((ext_vector_type(16))) float f32x16;
typedef __attribute__((ext_vector_type(4))) int int4v;
typedef __attribute__((ext_vector_type(8))) int int8v;

#if __has_builtin(__builtin_amdgcn_exp2f)
#define EXP2F(x) __builtin_amdgcn_exp2f(x)
#else
#define EXP2F(x) exp2f(x)
#endif

typedef __attribute__((address_space(1))) const void gvoid;
typedef __attribute__((address_space(3))) void lvoid;

__device__ __forceinline__ void gload16(const void* g, void* l) {
    // async global->LDS, 16B/lane; LDS dest is wave-uniform base + lane*16
    __builtin_amdgcn_global_load_lds((gvoid*)(uintptr_t)g, (lvoid*)(uintptr_t)l,
                                     16, 0, 0);
}

// fp4 e2m1 quantize (scale 1.0): grid {0,.5,1,1.5,2,3,4,6}, round-to-nearest.
// Exact rounding rule is irrelevant for correctness: norms are computed from
// the SAME quantized values, so diagonal l2 stays exactly 0.
__device__ __forceinline__ uint32_t q4(float x, float& dq) {
    float a = fabsf(x);
    uint32_t m; float v;
    if      (a < 0.25f) { m = 0; v = 0.0f; }
    else if (a < 0.75f) { m = 1; v = 0.5f; }
    else if (a < 1.25f) { m = 2; v = 1.0f; }
    else if (a < 1.75f) { m = 3; v = 1.5f; }
    else if (a < 2.5f)  { m = 4; v = 2.0f; }
    else if (a < 3.5f)  { m = 5; v = 3.0f; }
    else if (a < 5.0f)  { m = 6; v = 4.0f; }
    else                { m = 7; v = 6.0f; }
    if (x < 0.0f) { m |= 8u; v = -v; }
    dq = v;
    return m;
}

// ---------------- kernel 1: f32 -> fp4 e2m1 + row norms (from quantized vals)
__global__ void prep_kernel(const float* __restrict__ src, const float* __restrict__ tgt,
                            unsigned char* __restrict__ Sq, unsigned char* __restrict__ Tq,
                            float* __restrict__ nS, float* __restrict__ nT) {
    int wid = threadIdx.x >> 6, lane = threadIdx.x & 63;
    int row = blockIdx.x * 4 + wid;            // 0..16383
    const float* in; unsigned char* ob; float* on; int r;
    if (row < NR) { in = src; ob = Sq; on = nS; r = row; }
    else         { in = tgt; ob = Tq; on = nT; r = row - NR; }

    const float4* inr = (const float4*)(in + (size_t)r * 256);
    float4 v = inr[lane];                       // 4 consecutive f32
    float d0, d1, d2, d3;
    uint32_t c0 = q4(v.x, d0), c1 = q4(v.y, d1), c2 = q4(v.z, d2), c3 = q4(v.w, d3);
    float sq = d0 * d0 + d1 * d1 + d2 * d2 + d3 * d3;

    // 4 nibbles -> 2 bytes; even k in low nibble (any consistent k-order is OK)
    unsigned short pack = (unsigned short)((c0 | (c1 << 4)) | ((c2 | (c3 << 4)) << 8));
    *(unsigned short*)(ob + (size_t)r * RB + lane * 2) = pack;

    #pragma unroll
    for (int o = 32; o > 0; o >>= 1) sq += __shfl_xor(sq, o, 64);
    if (lane == 0) on[r] = -0.5f * LOG2E * sq;  // b_i = -(log2e/2)*||x_i||^2
}

// ---------------- tile decode
struct TileInfo {
    const unsigned char* A; const unsigned char* B;
    const float* na; const float* nb;
    float w; int rb, cb;
};

__device__ __forceinline__ void decode_tile(int bid,
    const unsigned char* Sq, const unsigned char* Tq,
    const float* nS, const float* nT, TileInfo& T)
{
    int idx = bid;
    if (bid < 2 * NT_SS) {
        if (bid >= NT_SS) idx -= NT_SS;
        int t = (int)((sqrtf(8.0f * (float)idx + 1.0f) - 1.0f) * 0.5f);
        while ((t + 1) * (t + 2) / 2 <= idx) ++t;
        while (t * (t + 1) / 2 > idx) --t;
        int ti = t, tj = idx - t * (t + 1) / 2;          // tj <= ti
        if (bid < NT_SS) { T.A = Sq; T.B = Sq; T.na = nS; T.nb = nS; }
        else             { T.A = Tq; T.B = Tq; T.na = nT; T.nb = nT; }
        T.w = (ti == tj) ? 1.0f : 2.0f;                  // symmetric double-count
        T.rb = ti * BM; T.cb = tj * BM;
    } else {
        idx = bid - 2 * NT_SS;
        T.A = Sq; T.B = Tq; T.na = nS; T.nb = nT;
        T.w = -2.0f;                                      // -2 * mean(s,t)
        T.rb = (idx >> 5) * BM; T.cb = (idx & 31) * BM;
    }
}

// ---------------- kernel 2: persistent 256x256 MX-fp4 MFMA GEMM + epilogue
// Each block owns ~8 consecutive tiles; tile t+1's panels stream into the
// other LDS buffer while tile t computes (counted vmcnt(8), raw s_barrier —
// never __syncthreads, which would drain vmcnt to 0).
// MFMA: mfma_scale_f32_32x32x64_f8f6f4, FMT=4 (fp4 e2m1), scale=127 (=2^0).
// LDS XOR swizzle (r2/r4/r5-validated geometry): LDS[row][16B-slot p] holds
// global slot p ^ (row&7); inverse applied on per-lane GLOBAL source address.
__global__ __launch_bounds__(512, 2) void mmd_tiles(
    const unsigned char* __restrict__ Sq, const unsigned char* __restrict__ Tq,
    const float* __restrict__ nS, const float* __restrict__ nT,
    float* __restrict__ parts)
{
    __shared__ __align__(16) unsigned char As[2][BM][RB];   // 64 KB
    __shared__ __align__(16) unsigned char Bs[2][BM][RB];   // 64 KB
    __shared__ float red[8];

    // XCD-contiguous persistent mapping: block b -> virtual id vb so each XCD
    // (b%8) owns a contiguous range of ~260 tiles (L2 panel locality).
    const int b = blockIdx.x;
    const int vb = (b & 7) * 32 + (b >> 3);
    const int t0 = vb * 8 + (vb >> 3);                     // 2080 = 256*8+32
    const int t1 = (vb + 1) * 8 + ((vb + 1) >> 3);
    const int nt = t1 - t0;

    const int tid = threadIdx.x;
    const int wid = tid >> 6, lane = tid & 63;
    const int wr = wid >> 2, wc = wid & 3;       // 2x4 waves; per-wave 128x64
    const int l31 = lane & 31, h2 = lane >> 5;   // MFMA row/col, k-half

    // staging: one gload16 covers 8 rows (64 lanes x 16B = 1KB)
    const int srow = lane >> 3;                   // 0..7
    const int sslot = (lane & 7) ^ srow;          // inverse swizzle on SOURCE
    const size_t laneOff = (size_t)srow * RB + (size_t)sslot * 16;

    f32x16 acc[4][2];
    {
        f32x16 z = {};
        #pragma unroll
        for (int m = 0; m < 4; ++m) { acc[m][0] = z; acc[m][1] = z; }
    }

    #define STAGE(bf, T)                                                        \
        do {                                                                    \
            const unsigned char* ag = (T).A + (size_t)(T).rb * RB + laneOff;    \
            const unsigned char* bg = (T).B + (size_t)(T).cb * RB + laneOff;    \
            _Pragma("unroll")                                                   \
            for (int c_ = 0; c_ < 4; ++c_) {                                    \
                int ch = wid * 4 + c_;            /* 8-row chunk 0..31 */       \
                gload16(ag + (size_t)(ch * 8) * RB, &As[bf][ch * 8][0]);        \
                gload16(bg + (size_t)(ch * 8) * RB, &Bs[bf][ch * 8][0]);        \
            }                                                                   \
        } while (0)

    TileInfo cur, nxt;
    decode_tile(t0, Sq, Tq, nS, nT, cur);
    nxt = cur;
    STAGE(0, cur);                                // prologue stage, tile t0

    float flsum = 0.0f;                           // per-lane sum across tiles

    for (int ii = 0; ii < nt; ++ii) {
        const int bufc = ii & 1;
        if (ii + 1 < nt) {
            decode_tile(t0 + ii + 1, Sq, Tq, nS, nT, nxt);
            STAGE(bufc ^ 1, nxt);                 // 8 more gloads in flight
            asm volatile("s_waitcnt vmcnt(8)" ::: "memory");  // my tile-ii loads done
        } else {
            asm volatile("s_waitcnt vmcnt(0)" ::: "memory");
        }
        __builtin_amdgcn_s_barrier();             // everyone's tile-ii loads done
        asm volatile("" ::: "memory");

        // ---- COMPUTE: K=256 = 4 slices of 64; 1 b128 per operand per MFMA
        {
            const unsigned char (*Ap)[RB] = As[bufc];
            const unsigned char (*Bp)[RB] = Bs[bufc];
            #pragma unroll
            for (int q = 0; q < 4; ++q) {
                const int4v z4 = (int4v){0, 0, 0, 0};
                int8v bop[2];
                #pragma unroll
                for (int ni = 0; ni < 2; ++ni) {
                    int rw = wc * 64 + ni * 32 + l31;
                    int p = ((2 * q + h2) ^ (rw & 7)) * 16;
                    int4v bv = *(const int4v*)(&Bp[rw][p]);
                    bop[ni] = __builtin_shufflevector(bv, z4, 0, 1, 2, 3, 4, 5, 6, 7);
                }
                #pragma unroll
                for (int mi = 0; mi < 4; ++mi) {
                    int rw = wr * 128 + mi * 32 + l31;
                    int p = ((2 * q + h2) ^ (rw & 7)) * 16;
                    int4v av = *(const int4v*)(&Ap[rw][p]);
                    int8v aop = __builtin_shufflevector(av, z4, 0, 1, 2, 3, 4, 5, 6, 7);
                    acc[mi][0] = __builtin_amdgcn_mfma_scale_f32_32x32x64_f8f6f4(
                        aop, bop[0], acc[mi][0], 4, 4, 0, 127, 0, 127);
                    acc[mi][1] = __builtin_amdgcn_mfma_scale_f32_32x32x64_f8f6f4(
                        aop, bop[1], acc[mi][1], 4, 4, 0, 127, 0, 127);
                }
            }
        }
        asm volatile("" ::: "memory");
        __builtin_amdgcn_s_barrier();             // LDS reads done; next STAGE may overwrite

        // ---- EPILOGUE (registers + tiny global loads only; no LDS)
        {
            float cy0 = cur.nb[cur.cb + wc * 64 + l31];
            float cy1 = cur.nb[cur.cb + wc * 64 + 32 + l31];
            float r0 = cur.na[cur.rb + wr * 128 + lane];
            float r1 = cur.na[cur.rb + wr * 128 + 64 + lane];
            float macc = -3.0e38f;
            #pragma unroll
            for (int mi = 0; mi < 4; ++mi)
                #pragma unroll
                for (int ni = 0; ni < 2; ++ni)
                    #pragma unroll
                    for (int r = 0; r < 16; ++r)
                        macc = fmaxf(macc, acc[mi][ni][r]);
            // arg = log2e*xy + bx_i + cy_j; all exp2 underflow to exact 0 if
            // max over wave region < -160 (reference also produces exact 0)
            float bound = fmaf(macc, LOG2E, fmaxf(r0, r1) + fmaxf(cy0, cy1));
            #pragma unroll
            for (int o = 32; o > 0; o >>= 1)
                bound = fmaxf(bound, __shfl_xor(bound, o, 64));

            if (bound >= -160.0f) {
                float s0 = 0.f, s1 = 0.f, s2 = 0.f, s3 = 0.f;
                #pragma unroll
                for (int mi = 0; mi < 4; ++mi) {
                    f32x4 bxv[4];
                    #pragma unroll
                    for (int g = 0; g < 4; ++g)
                        bxv[g] = *(const f32x4*)&cur.na[cur.rb + wr * 128 + mi * 32 + 4 * h2 + 8 * g];
                    #pragma unroll
                    for (int ni = 0; ni < 2; ++ni) {
                        float c0 = ni ? cy1 : cy0;
                        #pragma unroll
                        for (int r = 0; r < 16; ++r) {
                            float arg = fmaf(acc[mi][ni][r], LOG2E, bxv[r >> 2][r & 3] + c0);
                            float u = EXP2F(arg);
                            float t = fmaf(u, u, u);         // u^2 + u
                            if ((r & 3) == 0) s0 += t;
                            else if ((r & 3) == 1) s1 += t;
                            else if ((r & 3) == 2) s2 += t;
                            else s3 += t;
                        }
                    }
                }
                flsum += cur.w * ((s0 + s1) + (s2 + s3));
            }
            f32x16 z = {};
            #pragma unroll
            for (int m = 0; m < 4; ++m) { acc[m][0] = z; acc[m][1] = z; }
        }
        cur = nxt;
    }
    #undef STAGE

    #pragma unroll
    for (int o = 32; o > 0; o >>= 1) flsum += __shfl_xor(flsum, o, 64);
    if (lane == 0) red[wid] = flsum;
    __syncthreads();
    if (tid == 0) {
        float s = 0.0f;
        #pragma unroll
        for (int w = 0; w < 8; ++w) s += red[w];
        parts[b] = s;
    }
}

// ---------------- kernel 3: final deterministic reduction (256 parts)
__global__ void reduce_parts(const float* __restrict__ parts, float* __restrict__ out) {
    __shared__ float buf[NBLK];
    buf[threadIdx.x] = parts[threadIdx.x];
    __syncthreads();
    #pragma unroll
    for (int st = NBLK / 2; st > 0; st >>= 1) {
        if ((int)threadIdx.x < st) buf[threadIdx.x] += buf[threadIdx.x + st];
        __syncthreads();
    }
    if (threadIdx.x == 0) out[0] = buf[0] * (1.0f / 67108864.0f);  // /8192^2
}

extern "C" void kernel_launch(void* const* d_in, const int* in_sizes, int n_in,
                              void* d_out, int out_size, void* d_ws, size_t ws_size,
                              hipStream_t stream) {
    const float* src = (const float*)d_in[0];
    const float* tgt = (const float*)d_in[1];

    // ws layout: Sq (1MB) | Tq (1MB) | nS (32KB) | nT (32KB) | parts (1KB)
    char* w = (char*)d_ws;
    unsigned char* Sq = (unsigned char*)w;
    unsigned char* Tq = (unsigned char*)(w + (size_t)NR * RB);
    float* nS = (float*)(w + 2 * (size_t)NR * RB);
    float* nT = nS + NR;
    float* parts = nT + NR;

    hipLaunchKernelGGL(prep_kernel, dim3(NR * 2 / 4), dim3(256), 0, stream,
                       src, tgt, Sq, Tq, nS, nT);
    hipLaunchKernelGGL(mmd_tiles, dim3(NBLK), dim3(512), 0, stream,
                       Sq, Tq, nS, nT, parts);
    hipLaunchKernelGGL(reduce_parts, dim3(1), dim3(NBLK), 0, stream,
                       parts, (float*)d_out);
}